// Round 6
// baseline (159.132 us; speedup 1.0000x reference)
//
#include <hip/hip_runtime.h>
#include <hip/hip_bf16.h>
#include <math.h>

typedef unsigned short u16;
typedef unsigned int u32;
typedef __bf16 bf16x8 __attribute__((ext_vector_type(8)));
typedef float fx4 __attribute__((ext_vector_type(4)));

#define MFMA16(a, b, c) __builtin_amdgcn_mfma_f32_16x16x32_bf16(a, b, c, 0, 0, 0)

static constexpr int Bb = 2, Ss = 2048, Dd = 1024, Hh = 16, DKV = 256;
static constexpr int NQKV = 1536; // 1024 q | 256 k | 256 v
static constexpr int ROWS = Bb * Ss; // 4096
static constexpr float L2T_OVER = 0.0259525632f;  // log2(10000)/512
static constexpr float SC2 = 0.18033688f;         // 0.125 * log2(e)
static constexpr int PSTR = 76;                   // Ps row stride (bank-spread)
static constexpr int NUNITS = 80;                 // split-K units per (b,h)
static constexpr int NBLK_ATTN = NUNITS * 32;     // 2560

__device__ __forceinline__ u16 f2bf(float f) {   // RNE
    union { float f; u32 i; } v; v.f = f;
    u32 u = v.i;
    return (u16)((u + 0x7FFFu + ((u >> 16) & 1u)) >> 16);
}
__device__ __forceinline__ u16 bfr(float f) {    // RN (cheap), for P tiles
    return (u16)((__float_as_uint(f) + 0x8000u) >> 16);
}

// async global->LDS, 16B/lane; LDS dest wave-uniform base + lane*16
__device__ __forceinline__ void gl16(const u16* g, u16* l) {
    __builtin_amdgcn_global_load_lds(
        (const __attribute__((address_space(1))) void*)g,
        (__attribute__((address_space(3))) void*)l, 16, 0, 0);
}

template <int CTRL>
__device__ __forceinline__ float dppf(float x) {
    return __int_as_float(
        __builtin_amdgcn_mov_dpp(__float_as_int(x), CTRL, 0xF, 0xF, true));
}
__device__ __forceinline__ float rsum16(float x) {
    x += dppf<0xB1>(x);   // quad_perm [1,0,3,2]
    x += dppf<0x4E>(x);   // quad_perm [2,3,0,1]
    x += dppf<0x124>(x);  // row_ror:4
    x += dppf<0x128>(x);  // row_ror:8
    return x;
}

// ---------- merged pre: prep(x->xc bf16, pad bits) + 3 weight transposes ----------
__global__ void pre_kernel(const float* __restrict__ x, const float* __restrict__ Wq,
                           const float* __restrict__ Wk, const float* __restrict__ Wv,
                           u16* __restrict__ xc, u32* __restrict__ kpb,
                           u16* __restrict__ wAll) {
    __shared__ u16 tile[32][33];
    __shared__ int flag;
    int bid = blockIdx.x, t = threadIdx.x;
    if (bid < 4096) {
        int row = bid;
        if (t == 0) flag = 0;
        __syncthreads();
        float4 d = *(const float4*)(x + (size_t)row * Dd + t * 4);
        int any = 0;
        float a0 = d.x, a1 = d.y, a2 = d.z, a3 = d.w;
        if ((__float_as_uint(a0) & 0x7FFFFFFFu) > 0x7F800000u) { a0 = 0.f; any = 1; }
        if ((__float_as_uint(a1) & 0x7FFFFFFFu) > 0x7F800000u) { a1 = 0.f; any = 1; }
        if ((__float_as_uint(a2) & 0x7FFFFFFFu) > 0x7F800000u) { a2 = 0.f; any = 1; }
        if ((__float_as_uint(a3) & 0x7FFFFFFFu) > 0x7F800000u) { a3 = 0.f; any = 1; }
        if (any) atomicOr(&flag, 1);
        uint2 o;
        o.x = (u32)f2bf(a0) | ((u32)f2bf(a1) << 16);
        o.y = (u32)f2bf(a2) | ((u32)f2bf(a3) << 16);
        *(uint2*)(xc + (size_t)row * Dd + t * 4) = o;
        __syncthreads();
        if (t == 0 && flag) {
            int b = row >> 11, s = row & (Ss - 1);
            atomicOr(&kpb[b * 64 + (s >> 5)], 1u << (s & 31));
        }
        return;
    }
    // transposes: f32 (R x C) -> bf16 (C x R)
    const float* in; u16* out; int C, bx, by;
    if (bid < 5120) { int i = bid - 4096; in = Wq; out = wAll; C = Dd; bx = i & 31; by = i >> 5; }
    else if (bid < 5376) { int i = bid - 5120; in = Wk; out = wAll + (size_t)Dd * Dd; C = DKV; bx = i & 7; by = i >> 3; }
    else { int i = bid - 5376; in = Wv; out = wAll + (size_t)1280 * Dd; C = DKV; bx = i & 7; by = i >> 3; }
    int c0 = bx * 32, r0 = by * 32;
    int tx = t & 31, ty = t >> 5;
    for (int i = 0; i < 32; i += 8)
        tile[ty + i][tx] = f2bf(in[(size_t)(r0 + ty + i) * C + c0 + tx]);
    __syncthreads();
    for (int i = 0; i < 32; i += 8)
        out[(size_t)(c0 + ty + i) * Dd + r0 + tx] = tile[tx][ty + i];
}

// ------- fused QKV GEMM: qkv[4096,1536] = xc * wAll^T; BM=128 BN=64 BK=32 -------
__global__ __launch_bounds__(256) void gemm_qkv(
    const u16* __restrict__ A, const u16* __restrict__ Bt, u16* __restrict__ C) {
    __shared__ __align__(16) u16 As[2][128 * 32];
    __shared__ __align__(16) u16 Bs[2][64 * 32];
    int t = threadIdx.x, w = t >> 6, lane = t & 63;
    int l15 = lane & 15, quad = lane >> 4;
    int col0 = blockIdx.x * 64, row0 = blockIdx.y * 128;
    int wm = w >> 1, wn = w & 1;  // wave tile 64x32
    fx4 acc[4][2];
#pragma unroll
    for (int i = 0; i < 4; ++i)
#pragma unroll
        for (int j = 0; j < 2; ++j) acc[i][j] = (fx4){0.f, 0.f, 0.f, 0.f};

    auto stage = [&](int kb, int buf) {
#pragma unroll
        for (int i = 0; i < 2; ++i) {
            int slot = i * 256 + t;
            int row = slot >> 2, p = slot & 3, g = p ^ ((row >> 1) & 3);
            gl16(A + (size_t)(row0 + row) * Dd + kb * 32 + g * 8,
                 &As[buf][(i * 256 + w * 64) * 8]);
        }
        {
            int row = t >> 2, p = t & 3, g = p ^ ((row >> 1) & 3);
            gl16(Bt + (size_t)(col0 + row) * Dd + kb * 32 + g * 8,
                 &Bs[buf][(w * 64) * 8]);
        }
    };

    stage(0, 0);
    int buf = 0;
    for (int kb = 0; kb < 32; ++kb) {
        __syncthreads();
        if (kb + 1 < 32) stage(kb + 1, buf ^ 1);
        bf16x8 af[4], bfr2[2];
#pragma unroll
        for (int mi = 0; mi < 4; ++mi) {
            int row = wm * 64 + mi * 16 + l15;
            af[mi] = *(const bf16x8*)(&As[buf][row * 32 + ((quad ^ ((row >> 1) & 3)) * 8)]);
        }
#pragma unroll
        for (int ni = 0; ni < 2; ++ni) {
            int row = wn * 32 + ni * 16 + l15;
            bfr2[ni] = *(const bf16x8*)(&Bs[buf][row * 32 + ((quad ^ ((row >> 1) & 3)) * 8)]);
        }
#pragma unroll
        for (int mi = 0; mi < 4; ++mi)
#pragma unroll
            for (int ni = 0; ni < 2; ++ni)
                acc[mi][ni] = MFMA16(af[mi], bfr2[ni], acc[mi][ni]);
        buf ^= 1;
    }
#pragma unroll
    for (int mi = 0; mi < 4; ++mi) {
        int rbase = row0 + wm * 64 + mi * 16 + quad * 4;
#pragma unroll
        for (int ni = 0; ni < 2; ++ni) {
            int ccol = col0 + wn * 32 + ni * 16 + l15;
#pragma unroll
            for (int r = 0; r < 4; ++r)
                C[(size_t)(rbase + r) * NQKV + ccol] = f2bf(acc[mi][ni][r]);
        }
    }
}

// ---------- merged post: rope_k (k cols -> krope) + vtrans (v cols -> vtb) ----------
__global__ void post_kernel(const u16* __restrict__ qkv, u16* __restrict__ kr,
                            u16* __restrict__ vtb) {
    __shared__ u16 tile[32][33];
    int bid = blockIdx.x, t = threadIdx.x;
    if (bid < 4096) {
        int row = bid;
        float pos = (float)(row & (Ss - 1));
        float kv = __uint_as_float(((u32)qkv[(size_t)row * NQKV + Dd + t]) << 16);
        float j0 = (float)(2 * t), j1 = j0 + 1.0f;
        float f0 = exp2f(-j0 * L2T_OVER), f1 = exp2f(-j1 * L2T_OVER);
        float s0, c0, s1, c1;
        sincosf(pos * f0, &s0, &c0);
        sincosf(pos * f1, &s1, &c1);
        float r0 = kv * (c0 - s0), r1 = kv * (s0 + c0);
        float r2 = kv * (c1 - s1), r3 = kv * (s1 + c1);
        uint2 o;
        o.x = (u32)f2bf(r0) | ((u32)f2bf(r1) << 16);
        o.y = (u32)f2bf(r2) | ((u32)f2bf(r3) << 16);
        *(uint2*)(kr + (size_t)row * Dd + t * 4) = o;
        return;
    }
    int i = bid - 4096;
    int b = i >> 9, by = (i & 511) >> 3, bx = i & 7;
    int c0 = bx * 32, r0 = by * 32;
    int tx = t & 31, ty = t >> 5;
    for (int k = 0; k < 32; k += 8)
        tile[ty + k][tx] = qkv[(size_t)(b * Ss + r0 + ty + k) * NQKV + 1280 + c0 + tx];
    __syncthreads();
    for (int k = 0; k < 32; k += 8)
        vtb[(size_t)(b * DKV + c0 + ty + k) * Ss + r0 + tx] = tile[tx][ty + k];
}

// -------- Q fragment loader with in-register RoPE (pairs are lane-local) --------
__device__ __forceinline__ bf16x8 ropeFrag(uint4 raw, float pos, float jbase) {
    u32 W[4] = {raw.x, raw.y, raw.z, raw.w};
    union { u32 u[4]; bf16x8 v; } o;
#pragma unroll
    for (int c = 0; c < 4; ++c) {
        float x0 = __uint_as_float(W[c] << 16);
        float x1 = __uint_as_float(W[c] & 0xFFFF0000u);
        float f = exp2f(-(jbase + (float)c) * L2T_OVER);
        float sn, cs;
        sincosf(pos * f, &sn, &cs);
        float r0 = x0 * cs - x1 * sn, r1 = x0 * sn + x1 * cs;
        o.u[c] = (u32)f2bf(r0) | ((u32)f2bf(r1) << 16);
    }
    return o.v;
}

// ---------------- flash attention, fixed-M softmax, split-K ----------------
// grid 2560: col=bid&31 -> (b,h); ub=79-(bid>>5) -> (tile, unit), heavy first.
// Unit covers kb in [unit*8, min(unit*8+8, tile+1)). Fixed-M partials are
// additive across units -> reduce_kernel sums them. block 256 = 4 waves x 16 q.
__global__ __launch_bounds__(256) void attn_kernel(
    const u16* __restrict__ qkv, const u16* __restrict__ kr,
    const u16* __restrict__ vt, const u32* __restrict__ kpb,
    float* __restrict__ po, float* __restrict__ pl) {
    __shared__ __align__(16) u16 Ks[2][64 * 64];
    __shared__ __align__(16) u16 Vs[2][16 * 64];
    __shared__ __align__(16) u16 Ps[4][16 * PSTR];

    int t = threadIdx.x, w = t >> 6, lane = t & 63;
    int l15 = lane & 15, quad = lane >> 4;
    int bid = blockIdx.x;
    int col = bid & 31, b = col >> 4, h = col & 15;
    int ub = (NUNITS - 1) - (bid >> 5);
    int tile, unit;
    if (ub < 8) { tile = ub; unit = 0; }
    else if (ub < 24) { int v = ub - 8; tile = 8 + (v >> 1); unit = v & 1; }
    else if (ub < 48) { int v = ub - 24; int d3 = v / 3; tile = 16 + d3; unit = v - 3 * d3; }
    else { int v = ub - 48; tile = 24 + (v >> 2); unit = v & 3; }
    int q0 = tile * 64;
    int kbStart = unit * 8;
    int kbEnd = min(kbStart + 8, tile + 1);

    // Q A-frag with fused RoPE: m=l15 (q row), k=quad*8+j (dim)
    int pos = q0 + w * 16 + l15;
    const u16* qp = qkv + (size_t)(b * Ss + pos) * NQKV + h * 64;
    float jb = (float)(h * 32 + quad * 4);
    bf16x8 qf0 = ropeFrag(*(const uint4*)(qp + quad * 8), (float)pos, jb);
    bf16x8 qf1 = ropeFrag(*(const uint4*)(qp + 32 + quad * 8), (float)pos, jb + 16.f);

    auto stageK = [&](int k0, int buf) {
#pragma unroll
        for (int i2 = 0; i2 < 2; ++i2) {
            int row = i2 * 32 + w * 8 + (lane >> 3);
            int gg = (lane & 7) ^ (row & 7);
            gl16(kr + (size_t)(b * Ss + k0 + row) * Dd + h * 64 + gg * 8,
                 &Ks[buf][(i2 * 32 + w * 8) * 64]);
        }
    };
    auto stageV = [&](int k0, int buf) {
        if (w < 2) {
            int row = w * 8 + (lane >> 3);
            int gg = (lane & 7) ^ (row & 7);
            gl16(vt + (size_t)(b * DKV + h * 16 + row) * Ss + k0 + gg * 8,
                 &Vs[buf][(w * 8) * 64]);
        }
    };

    float l_lane[4] = {0.f, 0.f, 0.f, 0.f};  // per-lane partial sums (fixed M)
    fx4 oacc = (fx4){0.f, 0.f, 0.f, 0.f};

    stageK(kbStart * 64, 0);
    stageV(kbStart * 64, 0);
    int buf = 0;
    const int qrb = q0 + w * 16 + quad * 4;
    const int qmin = q0 + w * 16;

    for (int kb = kbStart; kb < kbEnd; ++kb) {
        int k0 = kb * 64;
        __syncthreads();  // drains prefetch vmcnt; prior LDS reads complete
        if (kb + 1 < kbEnd) { stageK(k0 + 64, buf ^ 1); stageV(k0 + 64, buf ^ 1); }

        // scores: per 16-key tile tt, C[row=quad*4+r][col=key l15]
        fx4 s[4];
#pragma unroll
        for (int tt = 0; tt < 4; ++tt) {
            const u16* kb_ = &Ks[buf][(tt * 16 + l15) * 64];
            bf16x8 kf0 = *(const bf16x8*)(kb_ + ((quad ^ (l15 & 7)) * 8));
            bf16x8 kf1 = *(const bf16x8*)(kb_ + (((quad + 4) ^ (l15 & 7)) * 8));
            fx4 z = (fx4){0.f, 0.f, 0.f, 0.f};
            fx4 a = MFMA16(qf0, kf0, z);
            s[tt] = MFMA16(qf1, kf1, a);
        }

        u32 pw0 = kpb[b * 64 + (k0 >> 5)];
        u32 pw1 = kpb[b * 64 + (k0 >> 5) + 1];
        bool fast = (k0 + 63 <= qmin) & ((pw0 | pw1) == 0u);

        // fixed-M: e = 2^(s*SC2 - 32); diag self-score >= 0 keeps dominant
        // term >= 2^-32; masked -> 0 (finite s, no NaN)
        float e[4][4];
        if (fast) {
#pragma unroll
            for (int tt = 0; tt < 4; ++tt)
#pragma unroll
                for (int r = 0; r < 4; ++r)
                    e[tt][r] = exp2f(fmaf(s[tt][r], SC2, -32.f));
        } else {
            u32 padb[4];
#pragma unroll
            for (int tt = 0; tt < 4; ++tt)
                padb[tt] = ((tt & 2 ? pw1 : pw0) >> ((tt * 16 + l15) & 31)) & 1u;
#pragma unroll
            for (int r = 0; r < 4; ++r) {
                int qq = qrb + r;
#pragma unroll
                for (int tt = 0; tt < 4; ++tt) {
                    float ee = exp2f(fmaf(s[tt][r], SC2, -32.f));
                    e[tt][r] = (k0 + tt * 16 + l15 <= qq && !padb[tt]) ? ee : 0.f;
                }
            }
        }

#pragma unroll
        for (int r = 0; r < 4; ++r) {
            l_lane[r] += (e[0][r] + e[1][r]) + (e[2][r] + e[3][r]);
            int prow = (quad * 4 + r) * PSTR + l15;
            Ps[w][prow + 0] = bfr(e[0][r]);
            Ps[w][prow + 16] = bfr(e[1][r]);
            Ps[w][prow + 32] = bfr(e[2][r]);
            Ps[w][prow + 48] = bfr(e[3][r]);
        }

        // PV: A=P[m=q l15][k=key], B=V[n=feat l15][k=key]; same-wave LDS, no barrier
#pragma unroll
        for (int hh2 = 0; hh2 < 2; ++hh2) {
            bf16x8 vf = *(const bf16x8*)(&Vs[buf][l15 * 64 + (((quad + 4 * hh2) ^ (l15 & 7)) * 8)]);
            bf16x8 pf = *(const bf16x8*)(&Ps[w][l15 * PSTR + hh2 * 32 + quad * 8]);
            oacc = MFMA16(pf, vf, oacc);
        }
        buf ^= 1;
    }

    // partial write: po[bid][qrow 64][feat 16], pl[bid][qrow 64]
#pragma unroll
    for (int r = 0; r < 4; ++r) {
        int qrow = w * 16 + quad * 4 + r;
        po[(size_t)bid * 1024 + qrow * 16 + l15] = oacc[r];
        float l_row = rsum16(l_lane[r]);
        if (l15 == 0) pl[bid * 64 + qrow] = l_row;
    }
}

// -------- reduce: sum <=4 unit partials per (tile,b,h), write replicated out --------
__global__ __launch_bounds__(256) void reduce_kernel(
    const float* __restrict__ po, const float* __restrict__ pl,
    float* __restrict__ out) {
    int rbid = blockIdx.x;
    int col = rbid & 31, tile = rbid >> 5;
    int b = col >> 4, h = col & 15;
    int base, n;
    if (tile < 8) { base = tile; n = 1; }
    else if (tile < 16) { base = 8 + (tile - 8) * 2; n = 2; }
    else if (tile < 24) { base = 24 + (tile - 16) * 3; n = 3; }
    else { base = 48 + (tile - 24) * 4; n = 4; }
    int t = threadIdx.x;
    int q = t >> 2, ug = (t & 3) * 4;
    float l = 0.f;
    fx4 o = (fx4){0.f, 0.f, 0.f, 0.f};
    for (int j = 0; j < n; ++j) {
        int slot = ((NUNITS - 1) - (base + j)) * 32 + col;
        l += pl[slot * 64 + q];
        fx4 v = *(const fx4*)(po + (size_t)slot * 1024 + q * 16 + ug);
        o += v;
    }
    float inv = 1.0f / l;
    size_t ob = (size_t)(b * Ss + tile * 64 + q) * Dd + h * 64 + ug * 4;
#pragma unroll
    for (int j = 0; j < 4; ++j) {
        float val = o[j] * inv;
        float4 o4 = {val, val, val, val};
        *(float4*)(out + ob + j * 4) = o4;
    }
}

// ---------------- launch ----------------
extern "C" void kernel_launch(void* const* d_in, const int* in_sizes, int n_in,
                              void* d_out, int out_size, void* d_ws, size_t ws_size,
                              hipStream_t stream) {
    const float* x = (const float*)d_in[0];
    const float* Wq = (const float*)d_in[1];
    const float* Wk = (const float*)d_in[2];
    const float* Wv = (const float*)d_in[3];
    float* out = (float*)d_out;

    char* ws = (char*)d_ws;
    const size_t SZ_XC = (size_t)ROWS * Dd * 2;    // 8 MiB (aliased by krope)
    const size_t SZ_KPB = 4096;
    const size_t SZ_WALL = (size_t)NQKV * Dd * 2;  // 3 MiB (aliased by vtb 2 MiB)
    const size_t SZ_QKV = (size_t)ROWS * NQKV * 2; // 12 MiB
    const size_t SZ_PO = (size_t)NBLK_ATTN * 1024 * 4; // 10 MiB
    const size_t SZ_PL = (size_t)NBLK_ATTN * 64 * 4;   // 640 KiB

    size_t off = 0;
    u16* xc = (u16*)(ws + off);
    u16* krope = (u16*)(ws + off); off += SZ_XC;   // alias: xc dead after gemm
    u32* kpb = (u32*)(ws + off); off += SZ_KPB;
    u16* wAll = (u16*)(ws + off);
    u16* vtb = (u16*)(ws + off); off += SZ_WALL;   // alias: wAll dead after gemm
    u16* qkv = (u16*)(ws + off); off += SZ_QKV;
    float* po = (float*)(ws + off); off += SZ_PO;
    float* pl = (float*)(ws + off); off += SZ_PL;
    (void)ws_size; (void)in_sizes; (void)n_in; (void)out_size;

    hipMemsetAsync(kpb, 0, 2 * 64 * 4, stream);
    pre_kernel<<<5632, 256, 0, stream>>>(x, Wq, Wk, Wv, xc, kpb, wAll);
    gemm_qkv<<<dim3(NQKV / 64, ROWS / 128), 256, 0, stream>>>(xc, wAll, qkv);
    post_kernel<<<5120, 256, 0, stream>>>(qkv, krope, vtb);
    attn_kernel<<<NBLK_ATTN, 256, 0, stream>>>(qkv, krope, vtb, kpb, po, pl);
    reduce_kernel<<<1024, 256, 0, stream>>>(po, pl, out);
}

// Round 10
// 155.142 us; speedup vs baseline: 1.0257x; 1.0257x over previous
//
#include <hip/hip_runtime.h>
#include <hip/hip_bf16.h>
#include <math.h>

typedef unsigned short u16;
typedef unsigned int u32;
typedef __bf16 bf16x8 __attribute__((ext_vector_type(8)));
typedef float fx4 __attribute__((ext_vector_type(4)));

#define MFMA16(a, b, c) __builtin_amdgcn_mfma_f32_16x16x32_bf16(a, b, c, 0, 0, 0)

static constexpr int Bb = 2, Ss = 2048, Dd = 1024, Hh = 16, DKV = 256;
static constexpr int NQKV = 1536; // 1024 q | 256 k | 256 v
static constexpr int ROWS = Bb * Ss; // 4096
static constexpr float L2T_OVER = 0.0259525632f;  // log2(10000)/512
static constexpr float SC2 = 0.18033688f;         // 0.125 * log2(e)
static constexpr int PSTR = 76;                   // Ps row stride (bank-spread)

__device__ __forceinline__ u16 f2bf(float f) {   // RNE
    union { float f; u32 i; } v; v.f = f;
    u32 u = v.i;
    return (u16)((u + 0x7FFFu + ((u >> 16) & 1u)) >> 16);
}
__device__ __forceinline__ u16 bfr(float f) {    // RN (cheap), for P tiles
    return (u16)((__float_as_uint(f) + 0x8000u) >> 16);
}

// async global->LDS, 16B/lane; LDS dest wave-uniform base + lane*16
__device__ __forceinline__ void gl16(const u16* g, u16* l) {
    __builtin_amdgcn_global_load_lds(
        (const __attribute__((address_space(1))) void*)g,
        (__attribute__((address_space(3))) void*)l, 16, 0, 0);
}

template <int CTRL>
__device__ __forceinline__ float dppf(float x) {
    return __int_as_float(
        __builtin_amdgcn_mov_dpp(__float_as_int(x), CTRL, 0xF, 0xF, true));
}
__device__ __forceinline__ float rsum16(float x) {
    x += dppf<0xB1>(x);   // quad_perm [1,0,3,2]
    x += dppf<0x4E>(x);   // quad_perm [2,3,0,1]
    x += dppf<0x124>(x);  // row_ror:4
    x += dppf<0x128>(x);  // row_ror:8
    return x;
}

// ---------- merged pre: prep(x->xc bf16, pad bits) + 3 weight transposes ----------
__global__ void pre_kernel(const float* __restrict__ x, const float* __restrict__ Wq,
                           const float* __restrict__ Wk, const float* __restrict__ Wv,
                           u16* __restrict__ xc, u32* __restrict__ kpb,
                           u16* __restrict__ wAll) {
    __shared__ u16 tile[32][33];
    __shared__ int flag;
    int bid = blockIdx.x, t = threadIdx.x;
    if (bid < 4096) {
        int row = bid;
        if (t == 0) flag = 0;
        __syncthreads();
        float4 d = *(const float4*)(x + (size_t)row * Dd + t * 4);
        int any = 0;
        float a0 = d.x, a1 = d.y, a2 = d.z, a3 = d.w;
        if ((__float_as_uint(a0) & 0x7FFFFFFFu) > 0x7F800000u) { a0 = 0.f; any = 1; }
        if ((__float_as_uint(a1) & 0x7FFFFFFFu) > 0x7F800000u) { a1 = 0.f; any = 1; }
        if ((__float_as_uint(a2) & 0x7FFFFFFFu) > 0x7F800000u) { a2 = 0.f; any = 1; }
        if ((__float_as_uint(a3) & 0x7FFFFFFFu) > 0x7F800000u) { a3 = 0.f; any = 1; }
        if (any) atomicOr(&flag, 1);
        uint2 o;
        o.x = (u32)f2bf(a0) | ((u32)f2bf(a1) << 16);
        o.y = (u32)f2bf(a2) | ((u32)f2bf(a3) << 16);
        *(uint2*)(xc + (size_t)row * Dd + t * 4) = o;
        __syncthreads();
        if (t == 0 && flag) {
            int b = row >> 11, s = row & (Ss - 1);
            atomicOr(&kpb[b * 64 + (s >> 5)], 1u << (s & 31));
        }
        return;
    }
    // transposes: f32 (R x C) -> bf16 (C x R)
    const float* in; u16* out; int C, bx, by;
    if (bid < 5120) { int i = bid - 4096; in = Wq; out = wAll; C = Dd; bx = i & 31; by = i >> 5; }
    else if (bid < 5376) { int i = bid - 5120; in = Wk; out = wAll + (size_t)Dd * Dd; C = DKV; bx = i & 7; by = i >> 3; }
    else { int i = bid - 5376; in = Wv; out = wAll + (size_t)1280 * Dd; C = DKV; bx = i & 7; by = i >> 3; }
    int c0 = bx * 32, r0 = by * 32;
    int tx = t & 31, ty = t >> 5;
    for (int i = 0; i < 32; i += 8)
        tile[ty + i][tx] = f2bf(in[(size_t)(r0 + ty + i) * C + c0 + tx]);
    __syncthreads();
    for (int i = 0; i < 32; i += 8)
        out[(size_t)(c0 + ty + i) * Dd + r0 + tx] = tile[tx][ty + i];
}

// ---------------- fused QKV GEMM: qkv[4096,1536] = xc * wAll^T ----------------
__global__ __launch_bounds__(256) void gemm_qkv(
    const u16* __restrict__ A, const u16* __restrict__ Bt, u16* __restrict__ C) {
    __shared__ __align__(16) u16 As[2][128 * 32];
    __shared__ __align__(16) u16 Bs[2][128 * 32];
    int t = threadIdx.x, w = t >> 6, lane = t & 63;
    int l15 = lane & 15, quad = lane >> 4;
    int col0 = blockIdx.x * 128, row0 = blockIdx.y * 128;
    int wm = w >> 1, wn = w & 1;
    fx4 acc[4][4];
#pragma unroll
    for (int i = 0; i < 4; ++i)
#pragma unroll
        for (int j = 0; j < 4; ++j) acc[i][j] = (fx4){0.f, 0.f, 0.f, 0.f};

    auto stage = [&](int kb, int buf) {
#pragma unroll
        for (int i = 0; i < 2; ++i) {
            int slot = i * 256 + t;
            int row = slot >> 2, p = slot & 3, g = p ^ ((row >> 1) & 3);
            gl16(A + (size_t)(row0 + row) * Dd + kb * 32 + g * 8,
                 &As[buf][(i * 256 + w * 64) * 8]);
            gl16(Bt + (size_t)(col0 + row) * Dd + kb * 32 + g * 8,
                 &Bs[buf][(i * 256 + w * 64) * 8]);
        }
    };

    stage(0, 0);
    int buf = 0;
    for (int kb = 0; kb < 32; ++kb) {
        __syncthreads();
        if (kb + 1 < 32) stage(kb + 1, buf ^ 1);
        bf16x8 af[4], bfr4[4];
#pragma unroll
        for (int mi = 0; mi < 4; ++mi) {
            int row = wm * 64 + mi * 16 + l15;
            af[mi] = *(const bf16x8*)(&As[buf][row * 32 + ((quad ^ ((row >> 1) & 3)) * 8)]);
        }
#pragma unroll
        for (int ni = 0; ni < 4; ++ni) {
            int row = wn * 64 + ni * 16 + l15;
            bfr4[ni] = *(const bf16x8*)(&Bs[buf][row * 32 + ((quad ^ ((row >> 1) & 3)) * 8)]);
        }
#pragma unroll
        for (int mi = 0; mi < 4; ++mi)
#pragma unroll
            for (int ni = 0; ni < 4; ++ni)
                acc[mi][ni] = MFMA16(af[mi], bfr4[ni], acc[mi][ni]);
        buf ^= 1;
    }
#pragma unroll
    for (int mi = 0; mi < 4; ++mi) {
        int rbase = row0 + wm * 64 + mi * 16 + quad * 4;
#pragma unroll
        for (int ni = 0; ni < 4; ++ni) {
            int ccol = col0 + wn * 64 + ni * 16 + l15;
#pragma unroll
            for (int r = 0; r < 4; ++r)
                C[(size_t)(rbase + r) * NQKV + ccol] = f2bf(acc[mi][ni][r]);
        }
    }
}

// ---------- merged post: rope_k (k cols -> krope) + vtrans (v cols -> vtb) ----------
__global__ void post_kernel(const u16* __restrict__ qkv, u16* __restrict__ kr,
                            u16* __restrict__ vtb) {
    __shared__ u16 tile[32][33];
    int bid = blockIdx.x, t = threadIdx.x;
    if (bid < 4096) {
        int row = bid;
        float pos = (float)(row & (Ss - 1));
        float kv = __uint_as_float(((u32)qkv[(size_t)row * NQKV + Dd + t]) << 16);
        float j0 = (float)(2 * t), j1 = j0 + 1.0f;
        float f0 = exp2f(-j0 * L2T_OVER), f1 = exp2f(-j1 * L2T_OVER);
        float s0, c0, s1, c1;
        sincosf(pos * f0, &s0, &c0);
        sincosf(pos * f1, &s1, &c1);
        float r0 = kv * (c0 - s0), r1 = kv * (s0 + c0);
        float r2 = kv * (c1 - s1), r3 = kv * (s1 + c1);
        uint2 o;
        o.x = (u32)f2bf(r0) | ((u32)f2bf(r1) << 16);
        o.y = (u32)f2bf(r2) | ((u32)f2bf(r3) << 16);
        *(uint2*)(kr + (size_t)row * Dd + t * 4) = o;
        return;
    }
    int i = bid - 4096;
    int b = i >> 9, by = (i & 511) >> 3, bx = i & 7;
    int c0 = bx * 32, r0 = by * 32;
    int tx = t & 31, ty = t >> 5;
    for (int k = 0; k < 32; k += 8)
        tile[ty + k][tx] = qkv[(size_t)(b * Ss + r0 + ty + k) * NQKV + 1280 + c0 + tx];
    __syncthreads();
    for (int k = 0; k < 32; k += 8)
        vtb[(size_t)(b * DKV + c0 + ty + k) * Ss + r0 + tx] = tile[tx][ty + k];
}

// -------- Q fragment loader with in-register RoPE (pairs are lane-local) --------
__device__ __forceinline__ bf16x8 ropeFrag(uint4 raw, float pos, float jbase) {
    u32 W[4] = {raw.x, raw.y, raw.z, raw.w};
    union { u32 u[4]; bf16x8 v; } o;
#pragma unroll
    for (int c = 0; c < 4; ++c) {
        float x0 = __uint_as_float(W[c] << 16);
        float x1 = __uint_as_float(W[c] & 0xFFFF0000u);
        float f = exp2f(-(jbase + (float)c) * L2T_OVER);
        float sn, cs;
        sincosf(pos * f, &sn, &cs);
        float r0 = x0 * cs - x1 * sn, r1 = x0 * sn + x1 * cs;
        o.u[c] = (u32)f2bf(r0) | ((u32)f2bf(r1) << 16);
    }
    return o.v;
}

// ---------------- flash attention, fixed-M softmax ----------------
// grid 1024: u=bid>>5 -> balanced tile perm (per-CU sums constant, heavy first)
// block 256 = 4 waves x 16 q; K-tile 64, double-buffered gl16 staging
__global__ __launch_bounds__(256) void attn_kernel(
    const u16* __restrict__ qkv, const u16* __restrict__ kr,
    const u16* __restrict__ vt, const u32* __restrict__ kpb,
    float* __restrict__ out) {
    __shared__ __align__(16) u16 Ks[2][64 * 64];
    __shared__ __align__(16) u16 Vs[2][16 * 64];
    __shared__ __align__(16) u16 Ps[4][16 * PSTR];

    int t = threadIdx.x, w = t >> 6, lane = t & 63;
    int l15 = lane & 15, quad = lane >> 4;
    int bid = blockIdx.x;
    int u = bid >> 5, g = u >> 3, i = u & 7;
    // balanced LPT perm: g0:31-i g1:16+i g2:15-i g3:i  (col sum of iters = 66)
    int tile = (g == 0) ? (31 - i) : (g == 1) ? (16 + i) : (g == 2) ? (15 - i) : i;
    int hh = bid & 31, b = hh >> 4, h = hh & 15;
    int q0 = tile * 64;
    int nkb = tile + 1;

    // Q A-frag with fused RoPE: m=l15 (q row), k=quad*8+j (dim)
    int pos = q0 + w * 16 + l15;
    const u16* qp = qkv + (size_t)(b * Ss + pos) * NQKV + h * 64;
    float jb = (float)(h * 32 + quad * 4);
    bf16x8 qf0 = ropeFrag(*(const uint4*)(qp + quad * 8), (float)pos, jb);
    bf16x8 qf1 = ropeFrag(*(const uint4*)(qp + 32 + quad * 8), (float)pos, jb + 16.f);

    auto stageK = [&](int k0, int buf) {
#pragma unroll
        for (int i2 = 0; i2 < 2; ++i2) {
            int row = i2 * 32 + w * 8 + (lane >> 3);
            int gg = (lane & 7) ^ (row & 7);
            gl16(kr + (size_t)(b * Ss + k0 + row) * Dd + h * 64 + gg * 8,
                 &Ks[buf][(i2 * 32 + w * 8) * 64]);
        }
    };
    auto stageV = [&](int k0, int buf) {
        if (w < 2) {
            int row = w * 8 + (lane >> 3);
            int gg = (lane & 7) ^ (row & 7);
            gl16(vt + (size_t)(b * DKV + h * 16 + row) * Ss + k0 + gg * 8,
                 &Vs[buf][(w * 8) * 64]);
        }
    };

    float l_lane[4] = {0.f, 0.f, 0.f, 0.f};  // per-lane partial sums (fixed M)
    fx4 oacc = (fx4){0.f, 0.f, 0.f, 0.f};

    stageK(0, 0);
    stageV(0, 0);
    int buf = 0;
    const int qrb = q0 + w * 16 + quad * 4;  // this lane's score-row q base
    const int qmin = q0 + w * 16;

    for (int kb = 0; kb < nkb; ++kb) {
        int k0 = kb * 64;
        __syncthreads();  // drains prefetch vmcnt; prior LDS reads complete
        if (kb + 1 < nkb) { stageK(k0 + 64, buf ^ 1); stageV(k0 + 64, buf ^ 1); }

        // scores: per 16-key tile tt, C[row=quad*4+r][col=key l15]
        fx4 s[4];
#pragma unroll
        for (int tt = 0; tt < 4; ++tt) {
            const u16* kb_ = &Ks[buf][(tt * 16 + l15) * 64];
            bf16x8 kf0 = *(const bf16x8*)(kb_ + ((quad ^ (l15 & 7)) * 8));
            bf16x8 kf1 = *(const bf16x8*)(kb_ + (((quad + 4) ^ (l15 & 7)) * 8));
            fx4 z = (fx4){0.f, 0.f, 0.f, 0.f};
            fx4 a = MFMA16(qf0, kf0, z);
            s[tt] = MFMA16(qf1, kf1, a);
        }

        u32 pw0 = kpb[b * 64 + (k0 >> 5)];
        u32 pw1 = kpb[b * 64 + (k0 >> 5) + 1];
        bool fast = (k0 + 63 <= qmin) & ((pw0 | pw1) == 0u);

        // fixed-M: e = 2^(s*SC2 - 32); softmax shift-invariant; dominant term
        // stays far above underflow; masked -> 0 via cndmask (finite s, no NaN)
        float e[4][4];
        if (fast) {
#pragma unroll
            for (int tt = 0; tt < 4; ++tt)
#pragma unroll
                for (int r = 0; r < 4; ++r)
                    e[tt][r] = exp2f(fmaf(s[tt][r], SC2, -32.f));
        } else {
            u32 padb[4];
#pragma unroll
            for (int tt = 0; tt < 4; ++tt)
                padb[tt] = ((tt & 2 ? pw1 : pw0) >> ((tt * 16 + l15) & 31)) & 1u;
#pragma unroll
            for (int r = 0; r < 4; ++r) {
                int qq = qrb + r;
#pragma unroll
                for (int tt = 0; tt < 4; ++tt) {
                    float ee = exp2f(fmaf(s[tt][r], SC2, -32.f));
                    e[tt][r] = (k0 + tt * 16 + l15 <= qq && !padb[tt]) ? ee : 0.f;
                }
            }
        }

#pragma unroll
        for (int r = 0; r < 4; ++r) {
            l_lane[r] += (e[0][r] + e[1][r]) + (e[2][r] + e[3][r]);
            int prow = (quad * 4 + r) * PSTR + l15;
            Ps[w][prow + 0] = bfr(e[0][r]);
            Ps[w][prow + 16] = bfr(e[1][r]);
            Ps[w][prow + 32] = bfr(e[2][r]);
            Ps[w][prow + 48] = bfr(e[3][r]);
        }

        // PV: A=P[m=q l15][k=key], B=V[n=feat l15][k=key]; same-wave LDS, no barrier
#pragma unroll
        for (int hh2 = 0; hh2 < 2; ++hh2) {
            bf16x8 vf = *(const bf16x8*)(&Vs[buf][l15 * 64 + (((quad + 4 * hh2) ^ (l15 & 7)) * 8)]);
            bf16x8 pf = *(const bf16x8*)(&Ps[w][l15 * PSTR + hh2 * 32 + quad * 8]);
            oacc = MFMA16(pf, vf, oacc);
        }
        buf ^= 1;
    }

    // epilogue: row sum reduce (once), then out = O_small[u] replicated x4 (f32)
#pragma unroll
    for (int r = 0; r < 4; ++r) {
        float l_row = rsum16(l_lane[r]);
        float a = oacc[r] / l_row;
        float4 o4 = {a, a, a, a};
        *(float4*)(out + (size_t)(b * Ss + qrb + r) * Dd + h * 64 + l15 * 4) = o4;
    }
}

// ---------------- launch ----------------
extern "C" void kernel_launch(void* const* d_in, const int* in_sizes, int n_in,
                              void* d_out, int out_size, void* d_ws, size_t ws_size,
                              hipStream_t stream) {
    const float* x = (const float*)d_in[0];
    const float* Wq = (const float*)d_in[1];
    const float* Wk = (const float*)d_in[2];
    const float* Wv = (const float*)d_in[3];
    float* out = (float*)d_out;

    char* ws = (char*)d_ws;
    const size_t SZ_XC = (size_t)ROWS * Dd * 2;    // 8 MiB (aliased by krope)
    const size_t SZ_KPB = 4096;
    const size_t SZ_WALL = (size_t)NQKV * Dd * 2;  // 3 MiB (aliased by vtb 2 MiB)
    const size_t SZ_QKV = (size_t)ROWS * NQKV * 2; // 12 MiB

    size_t off = 0;
    u16* xc = (u16*)(ws + off);
    u16* krope = (u16*)(ws + off); off += SZ_XC;   // alias: xc dead after gemm
    u32* kpb = (u32*)(ws + off); off += SZ_KPB;
    u16* wAll = (u16*)(ws + off);
    u16* vtb = (u16*)(ws + off); off += SZ_WALL;   // alias: wAll dead after gemm
    u16* qkv = (u16*)(ws + off); off += SZ_QKV;
    (void)ws_size; (void)in_sizes; (void)n_in; (void)out_size;

    hipMemsetAsync(kpb, 0, 2 * 64 * 4, stream);
    pre_kernel<<<5632, 256, 0, stream>>>(x, Wq, Wk, Wv, xc, kpb, wAll);
    gemm_qkv<<<dim3(NQKV / 128, ROWS / 128), 256, 0, stream>>>(xc, wAll, qkv);
    post_kernel<<<5120, 256, 0, stream>>>(qkv, krope, vtb);
    attn_kernel<<<1024, 256, 0, stream>>>(qkv, krope, vtb, kpb, out);
}

// Round 11
// 152.935 us; speedup vs baseline: 1.0405x; 1.0144x over previous
//
#include <hip/hip_runtime.h>
#include <hip/hip_bf16.h>
#include <math.h>

typedef unsigned short u16;
typedef unsigned int u32;
typedef __bf16 bf16x8 __attribute__((ext_vector_type(8)));
typedef float fx4 __attribute__((ext_vector_type(4)));

#define MFMA16(a, b, c) __builtin_amdgcn_mfma_f32_16x16x32_bf16(a, b, c, 0, 0, 0)

static constexpr int Bb = 2, Ss = 2048, Dd = 1024, Hh = 16, DKV = 256;
static constexpr int NQKV = 1536; // 1024 q | 256 k | 256 v
static constexpr int ROWS = Bb * Ss; // 4096
static constexpr float L2T_OVER = 0.0259525632f;  // log2(10000)/512
static constexpr float SC2 = 0.18033688f;         // 0.125 * log2(e)
static constexpr int PSTR = 76;                   // Ps row stride (bank-spread)

__device__ __forceinline__ u16 f2bf(float f) {   // RNE
    union { float f; u32 i; } v; v.f = f;
    u32 u = v.i;
    return (u16)((u + 0x7FFFu + ((u >> 16) & 1u)) >> 16);
}
__device__ __forceinline__ u16 bfr(float f) {    // RN (cheap), for P tiles
    return (u16)((__float_as_uint(f) + 0x8000u) >> 16);
}

// async global->LDS, 16B/lane; LDS dest wave-uniform base + lane*16
__device__ __forceinline__ void gl16(const u16* g, u16* l) {
    __builtin_amdgcn_global_load_lds(
        (const __attribute__((address_space(1))) void*)g,
        (__attribute__((address_space(3))) void*)l, 16, 0, 0);
}

template <int CTRL>
__device__ __forceinline__ float dppf(float x) {
    return __int_as_float(
        __builtin_amdgcn_mov_dpp(__float_as_int(x), CTRL, 0xF, 0xF, true));
}
__device__ __forceinline__ float rsum16(float x) {
    x += dppf<0xB1>(x);   // quad_perm [1,0,3,2]
    x += dppf<0x4E>(x);   // quad_perm [2,3,0,1]
    x += dppf<0x124>(x);  // row_ror:4
    x += dppf<0x128>(x);  // row_ror:8
    return x;
}

// ---------- merged pre: prep(x->xc bf16, pad bits) + 3 weight transposes ----------
__global__ void pre_kernel(const float* __restrict__ x, const float* __restrict__ Wq,
                           const float* __restrict__ Wk, const float* __restrict__ Wv,
                           u16* __restrict__ xc, u32* __restrict__ kpb,
                           u16* __restrict__ wAll) {
    __shared__ u16 tile[32][33];
    __shared__ int flag;
    int bid = blockIdx.x, t = threadIdx.x;
    if (bid < 4096) {
        int row = bid;
        if (t == 0) flag = 0;
        __syncthreads();
        float4 d = *(const float4*)(x + (size_t)row * Dd + t * 4);
        int any = 0;
        float a0 = d.x, a1 = d.y, a2 = d.z, a3 = d.w;
        if ((__float_as_uint(a0) & 0x7FFFFFFFu) > 0x7F800000u) { a0 = 0.f; any = 1; }
        if ((__float_as_uint(a1) & 0x7FFFFFFFu) > 0x7F800000u) { a1 = 0.f; any = 1; }
        if ((__float_as_uint(a2) & 0x7FFFFFFFu) > 0x7F800000u) { a2 = 0.f; any = 1; }
        if ((__float_as_uint(a3) & 0x7FFFFFFFu) > 0x7F800000u) { a3 = 0.f; any = 1; }
        if (any) atomicOr(&flag, 1);
        uint2 o;
        o.x = (u32)f2bf(a0) | ((u32)f2bf(a1) << 16);
        o.y = (u32)f2bf(a2) | ((u32)f2bf(a3) << 16);
        *(uint2*)(xc + (size_t)row * Dd + t * 4) = o;
        __syncthreads();
        if (t == 0 && flag) {
            int b = row >> 11, s = row & (Ss - 1);
            atomicOr(&kpb[b * 64 + (s >> 5)], 1u << (s & 31));
        }
        return;
    }
    // transposes: f32 (R x C) -> bf16 (C x R)
    const float* in; u16* out; int C, bx, by;
    if (bid < 5120) { int i = bid - 4096; in = Wq; out = wAll; C = Dd; bx = i & 31; by = i >> 5; }
    else if (bid < 5376) { int i = bid - 5120; in = Wk; out = wAll + (size_t)Dd * Dd; C = DKV; bx = i & 7; by = i >> 3; }
    else { int i = bid - 5376; in = Wv; out = wAll + (size_t)1280 * Dd; C = DKV; bx = i & 7; by = i >> 3; }
    int c0 = bx * 32, r0 = by * 32;
    int tx = t & 31, ty = t >> 5;
    for (int i = 0; i < 32; i += 8)
        tile[ty + i][tx] = f2bf(in[(size_t)(r0 + ty + i) * C + c0 + tx]);
    __syncthreads();
    for (int i = 0; i < 32; i += 8)
        out[(size_t)(c0 + ty + i) * Dd + r0 + tx] = tile[tx][ty + i];
}

// ------- fused QKV GEMM: qkv[4096,1536] = xc * wAll^T; BM=128 BN=64 BK=32 -------
// 768 blocks (3/CU) vs prior 384 — occupancy doubles; per-element accumulation
// order unchanged -> bit-identical qkv output.
__global__ __launch_bounds__(256) void gemm_qkv(
    const u16* __restrict__ A, const u16* __restrict__ Bt, u16* __restrict__ C) {
    __shared__ __align__(16) u16 As[2][128 * 32];
    __shared__ __align__(16) u16 Bs[2][64 * 32];
    int t = threadIdx.x, w = t >> 6, lane = t & 63;
    int l15 = lane & 15, quad = lane >> 4;
    int col0 = blockIdx.x * 64, row0 = blockIdx.y * 128;
    int wm = w >> 1, wn = w & 1;  // wave tile 64x32
    fx4 acc[4][2];
#pragma unroll
    for (int i = 0; i < 4; ++i)
#pragma unroll
        for (int j = 0; j < 2; ++j) acc[i][j] = (fx4){0.f, 0.f, 0.f, 0.f};

    auto stage = [&](int kb, int buf) {
#pragma unroll
        for (int i = 0; i < 2; ++i) {
            int slot = i * 256 + t;
            int row = slot >> 2, p = slot & 3, g = p ^ ((row >> 1) & 3);
            gl16(A + (size_t)(row0 + row) * Dd + kb * 32 + g * 8,
                 &As[buf][(i * 256 + w * 64) * 8]);
        }
        {
            int row = t >> 2, p = t & 3, g = p ^ ((row >> 1) & 3);
            gl16(Bt + (size_t)(col0 + row) * Dd + kb * 32 + g * 8,
                 &Bs[buf][(w * 64) * 8]);
        }
    };

    stage(0, 0);
    int buf = 0;
    for (int kb = 0; kb < 32; ++kb) {
        __syncthreads();
        if (kb + 1 < 32) stage(kb + 1, buf ^ 1);
        bf16x8 af[4], bfr2[2];
#pragma unroll
        for (int mi = 0; mi < 4; ++mi) {
            int row = wm * 64 + mi * 16 + l15;
            af[mi] = *(const bf16x8*)(&As[buf][row * 32 + ((quad ^ ((row >> 1) & 3)) * 8)]);
        }
#pragma unroll
        for (int ni = 0; ni < 2; ++ni) {
            int row = wn * 32 + ni * 16 + l15;
            bfr2[ni] = *(const bf16x8*)(&Bs[buf][row * 32 + ((quad ^ ((row >> 1) & 3)) * 8)]);
        }
#pragma unroll
        for (int mi = 0; mi < 4; ++mi)
#pragma unroll
            for (int ni = 0; ni < 2; ++ni)
                acc[mi][ni] = MFMA16(af[mi], bfr2[ni], acc[mi][ni]);
        buf ^= 1;
    }
#pragma unroll
    for (int mi = 0; mi < 4; ++mi) {
        int rbase = row0 + wm * 64 + mi * 16 + quad * 4;
#pragma unroll
        for (int ni = 0; ni < 2; ++ni) {
            int ccol = col0 + wn * 32 + ni * 16 + l15;
#pragma unroll
            for (int r = 0; r < 4; ++r)
                C[(size_t)(rbase + r) * NQKV + ccol] = f2bf(acc[mi][ni][r]);
        }
    }
}

// ---------- merged post: rope_k (k cols -> krope) + vtrans (v cols -> vtb) ----------
__global__ void post_kernel(const u16* __restrict__ qkv, u16* __restrict__ kr,
                            u16* __restrict__ vtb) {
    __shared__ u16 tile[32][33];
    int bid = blockIdx.x, t = threadIdx.x;
    if (bid < 4096) {
        int row = bid;
        float pos = (float)(row & (Ss - 1));
        float kv = __uint_as_float(((u32)qkv[(size_t)row * NQKV + Dd + t]) << 16);
        float j0 = (float)(2 * t), j1 = j0 + 1.0f;
        float f0 = exp2f(-j0 * L2T_OVER), f1 = exp2f(-j1 * L2T_OVER);
        float s0, c0, s1, c1;
        sincosf(pos * f0, &s0, &c0);
        sincosf(pos * f1, &s1, &c1);
        float r0 = kv * (c0 - s0), r1 = kv * (s0 + c0);
        float r2 = kv * (c1 - s1), r3 = kv * (s1 + c1);
        uint2 o;
        o.x = (u32)f2bf(r0) | ((u32)f2bf(r1) << 16);
        o.y = (u32)f2bf(r2) | ((u32)f2bf(r3) << 16);
        *(uint2*)(kr + (size_t)row * Dd + t * 4) = o;
        return;
    }
    int i = bid - 4096;
    int b = i >> 9, by = (i & 511) >> 3, bx = i & 7;
    int c0 = bx * 32, r0 = by * 32;
    int tx = t & 31, ty = t >> 5;
    for (int k = 0; k < 32; k += 8)
        tile[ty + k][tx] = qkv[(size_t)(b * Ss + r0 + ty + k) * NQKV + 1280 + c0 + tx];
    __syncthreads();
    for (int k = 0; k < 32; k += 8)
        vtb[(size_t)(b * DKV + c0 + ty + k) * Ss + r0 + tx] = tile[tx][ty + k];
}

// -------- Q fragment loader with in-register RoPE (pairs are lane-local) --------
__device__ __forceinline__ bf16x8 ropeFrag(uint4 raw, float pos, float jbase) {
    u32 W[4] = {raw.x, raw.y, raw.z, raw.w};
    union { u32 u[4]; bf16x8 v; } o;
#pragma unroll
    for (int c = 0; c < 4; ++c) {
        float x0 = __uint_as_float(W[c] << 16);
        float x1 = __uint_as_float(W[c] & 0xFFFF0000u);
        float f = exp2f(-(jbase + (float)c) * L2T_OVER);
        float sn, cs;
        sincosf(pos * f, &sn, &cs);
        float r0 = x0 * cs - x1 * sn, r1 = x0 * sn + x1 * cs;
        o.u[c] = (u32)f2bf(r0) | ((u32)f2bf(r1) << 16);
    }
    return o.v;
}

// ---------------- flash attention, fixed-M softmax ----------------
// grid 1024: u=bid>>5 -> balanced tile perm (per-CU sums constant, heavy first)
// block 256 = 4 waves x 16 q; K-tile 64, double-buffered gl16 staging
__global__ __launch_bounds__(256) void attn_kernel(
    const u16* __restrict__ qkv, const u16* __restrict__ kr,
    const u16* __restrict__ vt, const u32* __restrict__ kpb,
    float* __restrict__ out) {
    __shared__ __align__(16) u16 Ks[2][64 * 64];
    __shared__ __align__(16) u16 Vs[2][16 * 64];
    __shared__ __align__(16) u16 Ps[4][16 * PSTR];

    int t = threadIdx.x, w = t >> 6, lane = t & 63;
    int l15 = lane & 15, quad = lane >> 4;
    int bid = blockIdx.x;
    int u = bid >> 5, g = u >> 3, i = u & 7;
    // balanced LPT perm: g0:31-i g1:16+i g2:15-i g3:i  (col sum of iters = 66)
    int tile = (g == 0) ? (31 - i) : (g == 1) ? (16 + i) : (g == 2) ? (15 - i) : i;
    int hh = bid & 31, b = hh >> 4, h = hh & 15;
    int q0 = tile * 64;
    int nkb = tile + 1;

    // Q A-frag with fused RoPE: m=l15 (q row), k=quad*8+j (dim)
    int pos = q0 + w * 16 + l15;
    const u16* qp = qkv + (size_t)(b * Ss + pos) * NQKV + h * 64;
    float jb = (float)(h * 32 + quad * 4);
    bf16x8 qf0 = ropeFrag(*(const uint4*)(qp + quad * 8), (float)pos, jb);
    bf16x8 qf1 = ropeFrag(*(const uint4*)(qp + 32 + quad * 8), (float)pos, jb + 16.f);

    // pad bitmask preloaded once: lane i holds kpb[b*64+i]; per-iter via __shfl
    u32 pw_all = kpb[b * 64 + lane];

    auto stageK = [&](int k0, int buf) {
#pragma unroll
        for (int i2 = 0; i2 < 2; ++i2) {
            int row = i2 * 32 + w * 8 + (lane >> 3);
            int gg = (lane & 7) ^ (row & 7);
            gl16(kr + (size_t)(b * Ss + k0 + row) * Dd + h * 64 + gg * 8,
                 &Ks[buf][(i2 * 32 + w * 8) * 64]);
        }
    };
    auto stageV = [&](int k0, int buf) {
        if (w < 2) {
            int row = w * 8 + (lane >> 3);
            int gg = (lane & 7) ^ (row & 7);
            gl16(vt + (size_t)(b * DKV + h * 16 + row) * Ss + k0 + gg * 8,
                 &Vs[buf][(w * 8) * 64]);
        }
    };

    float l_lane[4] = {0.f, 0.f, 0.f, 0.f};  // per-lane partial sums (fixed M)
    fx4 oacc = (fx4){0.f, 0.f, 0.f, 0.f};

    stageK(0, 0);
    stageV(0, 0);
    int buf = 0;
    const int qrb = q0 + w * 16 + quad * 4;  // this lane's score-row q base
    const int qmin = q0 + w * 16;

    for (int kb = 0; kb < nkb; ++kb) {
        int k0 = kb * 64;
        __syncthreads();  // drains prefetch vmcnt; prior LDS reads complete
        if (kb + 1 < nkb) { stageK(k0 + 64, buf ^ 1); stageV(k0 + 64, buf ^ 1); }

        // scores: per 16-key tile tt, C[row=quad*4+r][col=key l15]
        fx4 s[4];
#pragma unroll
        for (int tt = 0; tt < 4; ++tt) {
            const u16* kb_ = &Ks[buf][(tt * 16 + l15) * 64];
            bf16x8 kf0 = *(const bf16x8*)(kb_ + ((quad ^ (l15 & 7)) * 8));
            bf16x8 kf1 = *(const bf16x8*)(kb_ + (((quad + 4) ^ (l15 & 7)) * 8));
            fx4 z = (fx4){0.f, 0.f, 0.f, 0.f};
            fx4 a = MFMA16(qf0, kf0, z);
            s[tt] = MFMA16(qf1, kf1, a);
        }

        u32 pw0 = (u32)__shfl((int)pw_all, 2 * kb, 64);
        u32 pw1 = (u32)__shfl((int)pw_all, 2 * kb + 1, 64);
        bool fast = (k0 + 63 <= qmin) & ((pw0 | pw1) == 0u);

        // fixed-M: e = 2^(s*SC2 - 32); softmax shift-invariant; dominant term
        // stays far above underflow; masked -> 0 via cndmask (finite s, no NaN)
        float e[4][4];
        if (fast) {
#pragma unroll
            for (int tt = 0; tt < 4; ++tt)
#pragma unroll
                for (int r = 0; r < 4; ++r)
                    e[tt][r] = exp2f(fmaf(s[tt][r], SC2, -32.f));
        } else {
            u32 padb[4];
#pragma unroll
            for (int tt = 0; tt < 4; ++tt)
                padb[tt] = ((tt & 2 ? pw1 : pw0) >> ((tt * 16 + l15) & 31)) & 1u;
#pragma unroll
            for (int r = 0; r < 4; ++r) {
                int qq = qrb + r;
#pragma unroll
                for (int tt = 0; tt < 4; ++tt) {
                    float ee = exp2f(fmaf(s[tt][r], SC2, -32.f));
                    e[tt][r] = (k0 + tt * 16 + l15 <= qq && !padb[tt]) ? ee : 0.f;
                }
            }
        }

#pragma unroll
        for (int r = 0; r < 4; ++r) {
            l_lane[r] += (e[0][r] + e[1][r]) + (e[2][r] + e[3][r]);
            int prow = (quad * 4 + r) * PSTR + l15;
            Ps[w][prow + 0] = bfr(e[0][r]);
            Ps[w][prow + 16] = bfr(e[1][r]);
            Ps[w][prow + 32] = bfr(e[2][r]);
            Ps[w][prow + 48] = bfr(e[3][r]);
        }

        // PV: A=P[m=q l15][k=key], B=V[n=feat l15][k=key]; same-wave LDS, no barrier
#pragma unroll
        for (int hh2 = 0; hh2 < 2; ++hh2) {
            bf16x8 vf = *(const bf16x8*)(&Vs[buf][l15 * 64 + (((quad + 4 * hh2) ^ (l15 & 7)) * 8)]);
            bf16x8 pf = *(const bf16x8*)(&Ps[w][l15 * PSTR + hh2 * 32 + quad * 8]);
            oacc = MFMA16(pf, vf, oacc);
        }
        buf ^= 1;
    }

    // epilogue: row sum reduce (once), then out = O_small[u] replicated x4 (f32)
#pragma unroll
    for (int r = 0; r < 4; ++r) {
        float l_row = rsum16(l_lane[r]);
        float a = oacc[r] / l_row;
        float4 o4 = {a, a, a, a};
        *(float4*)(out + (size_t)(b * Ss + qrb + r) * Dd + h * 64 + l15 * 4) = o4;
    }
}

// ---------------- launch ----------------
extern "C" void kernel_launch(void* const* d_in, const int* in_sizes, int n_in,
                              void* d_out, int out_size, void* d_ws, size_t ws_size,
                              hipStream_t stream) {
    const float* x = (const float*)d_in[0];
    const float* Wq = (const float*)d_in[1];
    const float* Wk = (const float*)d_in[2];
    const float* Wv = (const float*)d_in[3];
    float* out = (float*)d_out;

    char* ws = (char*)d_ws;
    const size_t SZ_XC = (size_t)ROWS * Dd * 2;    // 8 MiB (aliased by krope)
    const size_t SZ_KPB = 4096;
    const size_t SZ_WALL = (size_t)NQKV * Dd * 2;  // 3 MiB (aliased by vtb 2 MiB)
    const size_t SZ_QKV = (size_t)ROWS * NQKV * 2; // 12 MiB

    size_t off = 0;
    u16* xc = (u16*)(ws + off);
    u16* krope = (u16*)(ws + off); off += SZ_XC;   // alias: xc dead after gemm
    u32* kpb = (u32*)(ws + off); off += SZ_KPB;
    u16* wAll = (u16*)(ws + off);
    u16* vtb = (u16*)(ws + off); off += SZ_WALL;   // alias: wAll dead after gemm
    u16* qkv = (u16*)(ws + off); off += SZ_QKV;
    (void)ws_size; (void)in_sizes; (void)n_in; (void)out_size;

    hipMemsetAsync(kpb, 0, 2 * 64 * 4, stream);
    pre_kernel<<<5632, 256, 0, stream>>>(x, Wq, Wk, Wv, xc, kpb, wAll);
    gemm_qkv<<<dim3(NQKV / 64, ROWS / 128), 256, 0, stream>>>(xc, wAll, qkv);
    post_kernel<<<5120, 256, 0, stream>>>(qkv, krope, vtb);
    attn_kernel<<<1024, 256, 0, stream>>>(qkv, krope, vtb, kpb, out);
}